// Round 6
// baseline (5466.376 us; speedup 1.0000x reference)
//
#include <hip/hip_runtime.h>
#include <hip/hip_bf16.h>
#include <math.h>

#define STEPS 2048
#define BATCH 512
#define SH 136   // h1F/h2F per-column stride in shorts (272 B, 16B-aligned, 2-way banks)
#define SB 100   // hb per-column stride in floats (400 B, 16B-aligned)

typedef __attribute__((ext_vector_type(8))) short short8;
typedef __attribute__((ext_vector_type(4))) short short4v;
typedef __attribute__((ext_vector_type(2))) short short2v;
typedef __attribute__((ext_vector_type(4))) float f32x4;

__device__ __forceinline__ short f2bf(float f) {
    union { float f; unsigned u; } v; v.f = f;
    unsigned u = v.u;
    return (short)((u + 0x7FFFu + ((u >> 16) & 1u)) >> 16);  // RNE
}
__device__ __forceinline__ short2v pk2(float a, float b) {
    __hip_bfloat162 h = __float22bfloat162_rn(make_float2(a, b));
    union { __hip_bfloat162 h; short2v s; } u; u.h = h; return u.s;
}

// ---------------------------------------------------------------------------
// baseflow[b] = 25th percentile (linear interp) of flow[:, b]
// ---------------------------------------------------------------------------
__global__ __launch_bounds__(256) void baseflow_kernel(
    const float* __restrict__ hyd, float* __restrict__ bf)
{
    __shared__ float arr[STEPS];
    const int b = blockIdx.x;
    const int tid = threadIdx.x;
    for (int t = tid; t < STEPS; t += 256)
        arr[t] = hyd[(size_t)(t * BATCH + b) * 17];
    __syncthreads();
    for (int k = 2; k <= STEPS; k <<= 1) {
        for (int j = k >> 1; j > 0; j >>= 1) {
            for (int i = tid; i < STEPS; i += 256) {
                int ixj = i ^ j;
                if (ixj > i) {
                    float a = arr[i], c = arr[ixj];
                    bool up = ((i & k) == 0);
                    if (up ? (a > c) : (a < c)) { arr[i] = c; arr[ixj] = a; }
                }
            }
            __syncthreads();
        }
    }
    if (tid == 0) bf[b] = arr[511] + 0.75f * (arr[512] - arr[511]);
}

// ---------------------------------------------------------------------------
// SINGLE-WAVE dataflow kernel: 32 blocks x 64 threads; one wave owns 16
// batch columns for all 2048 steps. No __syncthreads() anywhere — all
// layer transposes are in-wave LDS round-trips ordered by lgkmcnt.
//   A layout: A[m=lane&15][k=(lane>>4)*8+j]
//   B layout: B[k=(lane>>4)*8+j][n=lane&15]
//   C layout: C[row=(lane>>4)*4+r][col=lane&15]   (same column stays on lane)
// Weights resident in register A-frags. Folds into W0's K-dim:
//   k 16..23 : 0.01 * W0[:,16..23]  (store scaling)
//   k 24     : b0                    (bias via B[24][n] = 1.0)
// x_{t+1}/rain prefetched from global one full step ahead.
// ---------------------------------------------------------------------------
__global__ __launch_bounds__(64, 1) void hyd_step_kernel(
    const float* __restrict__ hyd,
    const float* __restrict__ W0,  const float* __restrict__ b0,
    const float* __restrict__ W1,  const float* __restrict__ b1,
    const float* __restrict__ Win, const float* __restrict__ bin,
    const float* __restrict__ Wout,const float* __restrict__ bout,
    const float* __restrict__ baseflow,
    float* __restrict__ out)
{
    __shared__ __align__(16) short h1F[16 * SH];
    __shared__ __align__(16) short h2F[16 * SH];
    __shared__ __align__(16) float hb[16 * SB];  // m<9: exp(logit); m>=9: sigmoid

    const int lane = threadIdx.x;
    const int n = lane & 15;          // batch column within block
    const int q = lane >> 4;          // quad group
    const int bcol = blockIdx.x * 16 + n;

    // ---- one-time register preload: A-fragments + bias C-inits ----
    short8 a0[8];                 // W0 augmented (0.01-fold + b0 at k=24)
    short8 a1[8][4]; f32x4 c1[8]; // W1, b1
    short8 ah[6][4]; f32x4 ch[6]; // heads (rows 0..8 Win, 9..88 Wout)
    #pragma unroll
    for (int mt = 0; mt < 8; ++mt) {
        const int row = mt * 16 + n;
        #pragma unroll
        for (int j = 0; j < 8; ++j) {
            const int k = q * 8 + j;
            float w;
            if (k < 16)       w = W0[row * 24 + k];
            else if (k < 24)  w = 0.01f * W0[row * 24 + k];
            else if (k == 24) w = b0[row];
            else              w = 0.f;
            a0[mt][j] = f2bf(w);
        }
        #pragma unroll
        for (int kt = 0; kt < 4; ++kt)
            #pragma unroll
            for (int j = 0; j < 8; ++j)
                a1[mt][kt][j] = f2bf(W1[row * 128 + kt * 32 + q * 8 + j]);
        #pragma unroll
        for (int r = 0; r < 4; ++r) c1[mt][r] = b1[mt * 16 + q * 4 + r];
    }
    #pragma unroll
    for (int ht = 0; ht < 6; ++ht) {
        const int row = ht * 16 + n;
        #pragma unroll
        for (int kt = 0; kt < 4; ++kt)
            #pragma unroll
            for (int j = 0; j < 8; ++j) {
                const int k = kt * 32 + q * 8 + j;
                float w = 0.f;
                if (row < 9)       w = Win[row * 128 + k];
                else if (row < 89) w = Wout[(row - 9) * 128 + k];
                ah[ht][kt][j] = f2bf(w);
            }
        #pragma unroll
        for (int r = 0; r < 4; ++r) {
            const int m = ht * 16 + q * 4 + r;
            float bb = 0.f;
            if (m < 9)       bb = bin[m];
            else if (m < 89) bb = bout[m - 9];
            ch[ht][r] = bb;
        }
    }

    // ---- recurrent state: every lane holds the full stores of its column ----
    float sreg[8];
    #pragma unroll
    for (int j = 0; j < 8; ++j) sreg[j] = (j == 1) ? 1.f : 0.f;
    short8 sp;   // bf16(stores) — raw, 0.01 folded into W0
    #pragma unroll
    for (int jj = 0; jj < 4; ++jj) {
        short2v p = pk2(sreg[2 * jj], sreg[2 * jj + 1]);
        sp[2 * jj] = p[0]; sp[2 * jj + 1] = p[1];
    }
    short8 onef = (short8)0; onef[0] = (short)0x3F80;   // B[24][n] = 1.0
    const float bfv = baseflow[bcol];

    // ---- x/rain prefetch (one step ahead) ----
    const float* colbase = hyd + (size_t)bcol * 17 + 1;   // -> x[t][bcol][0]
    float xf[8] = {0, 0, 0, 0, 0, 0, 0, 0};
    if (q < 2) {
        #pragma unroll
        for (int j = 0; j < 8; ++j) xf[j] = colbase[q * 8 + j];
    }
    float rainN = colbase[0];

    #pragma unroll 1
    for (int t = 0; t < STEPS; ++t) {
        const float rain = rainN;
        // pack current x into B-frag halves (valid on q<2 lanes)
        short8 xq;
        #pragma unroll
        for (int jj = 0; jj < 4; ++jj) {
            short2v p = pk2(xf[2 * jj], xf[2 * jj + 1]);
            xq[2 * jj] = p[0]; xq[2 * jj + 1] = p[1];
        }
        // issue prefetch for t+1 (lands well before next step's L0)
        const int tn = (t + 1 < STEPS) ? (t + 1) : t;
        const float* pnext = colbase + (size_t)tn * (BATCH * 17);
        float nx[8] = {0, 0, 0, 0, 0, 0, 0, 0};
        if (q < 2) {
            #pragma unroll
            for (int j = 0; j < 8; ++j) nx[j] = pnext[q * 8 + j];
        }
        const float nrain = pnext[0];

        // === L0: h1 = relu(W0aug @ [x, stores, 1]) ===
        short8 bf0 = (q < 2) ? xq : ((q == 2) ? sp : onef);
        #pragma unroll
        for (int mt = 0; mt < 8; ++mt) {
            f32x4 z = {0.f, 0.f, 0.f, 0.f};
            f32x4 acc = __builtin_amdgcn_mfma_f32_16x16x32_bf16(a0[mt], bf0, z, 0, 0, 0);
            short4v p;
            short2v pa = pk2(fmaxf(acc[0], 0.f), fmaxf(acc[1], 0.f));
            short2v pb = pk2(fmaxf(acc[2], 0.f), fmaxf(acc[3], 0.f));
            p[0] = pa[0]; p[1] = pa[1]; p[2] = pb[0]; p[3] = pb[1];
            *(short4v*)&h1F[n * SH + mt * 16 + q * 4] = p;   // [col][m]
        }

        // === L1: h2 = relu(W1 @ h1 + b1) ===  (in-wave LDS transpose)
        short8 bh1[4];
        #pragma unroll
        for (int kt = 0; kt < 4; ++kt)
            bh1[kt] = *(const short8*)&h1F[n * SH + kt * 32 + q * 8];
        #pragma unroll
        for (int mt = 0; mt < 8; ++mt) {
            f32x4 acc = c1[mt];
            #pragma unroll
            for (int kt = 0; kt < 4; ++kt)
                acc = __builtin_amdgcn_mfma_f32_16x16x32_bf16(a1[mt][kt], bh1[kt], acc, 0, 0, 0);
            short4v p;
            short2v pa = pk2(fmaxf(acc[0], 0.f), fmaxf(acc[1], 0.f));
            short2v pb = pk2(fmaxf(acc[2], 0.f), fmaxf(acc[3], 0.f));
            p[0] = pa[0]; p[1] = pa[1]; p[2] = pb[0]; p[3] = pb[1];
            *(short4v*)&h2F[n * SH + mt * 16 + q * 4] = p;
        }

        // === heads: exp(logits) m<9, sigmoid(gates) 9<=m<89 ===
        short8 bh2[4];
        #pragma unroll
        for (int kt = 0; kt < 4; ++kt)
            bh2[kt] = *(const short8*)&h2F[n * SH + kt * 32 + q * 8];
        #pragma unroll
        for (int ht = 0; ht < 6; ++ht) {
            f32x4 acc = ch[ht];
            #pragma unroll
            for (int kt = 0; kt < 4; ++kt)
                acc = __builtin_amdgcn_mfma_f32_16x16x32_bf16(ah[ht][kt], bh2[kt], acc, 0, 0, 0);
            float4 o;
            #pragma unroll
            for (int r = 0; r < 4; ++r) {
                const int m = ht * 16 + q * 4 + r;
                const float v = acc[r];
                const bool isl = (m < 9);
                const float em = __expf(isl ? v : -v);
                ((float*)&o)[r] = isl ? em : __builtin_amdgcn_rcpf(1.f + em);
            }
            *(float4*)&hb[n * SB + ht * 16 + q * 4] = o;
        }

        // === tail: per-lane redundant, full column in registers ===
        {
            float gv[92];
            const float4* hp = (const float4*)&hb[n * SB];
            #pragma unroll
            for (int c2 = 0; c2 < 23; ++c2)
                ((float4*)gv)[c2] = hp[c2];

            float den = ((gv[0] + gv[1]) + (gv[2] + gv[3])) +
                        ((gv[4] + gv[5]) + (gv[6] + gv[7])) + gv[8];
            float rr = rain * __builtin_amdgcn_rcpf(den);
            #pragma unroll
            for (int j = 0; j < 8; ++j) sreg[j] += gv[1 + j] * rr;

            #pragma unroll
            for (int d = 0; d < 8; ++d) {
                float fb[8];
                #pragma unroll
                for (int j = 0; j < 8; ++j) fb[j] = gv[9 + d * 8 + j] * sreg[j];
                float fs = ((fb[0] + fb[1]) + (fb[2] + fb[3])) +
                           ((fb[4] + fb[5]) + (fb[6] + fb[7]));
                #pragma unroll
                for (int j = 0; j < 8; ++j) sreg[j] -= fb[j];
                sreg[d] += fs;
            }
            #pragma unroll
            for (int j = 0; j < 8; ++j) sreg[j] -= gv[73 + j] * sreg[j];   // escape
            float fd[8];
            #pragma unroll
            for (int j = 0; j < 8; ++j) fd[j] = gv[81 + j] * sreg[j];      // flow
            float fsum = ((fd[0] + fd[1]) + (fd[2] + fd[3])) +
                         ((fd[4] + fd[5]) + (fd[6] + fd[7]));
            #pragma unroll
            for (int j = 0; j < 8; ++j) sreg[j] -= fd[j];
            if (t == 0) sreg[2] = bfv / fmaxf(gv[83], 1e-5f);   // b_flow[SLOW=2]

            if (q == 0) out[(size_t)t * BATCH + bcol] = fsum;

            #pragma unroll
            for (int jj = 0; jj < 4; ++jj) {
                short2v p = pk2(sreg[2 * jj], sreg[2 * jj + 1]);
                sp[2 * jj] = p[0]; sp[2 * jj + 1] = p[1];
            }
        }

        // roll prefetch registers
        #pragma unroll
        for (int j = 0; j < 8; ++j) xf[j] = nx[j];
        rainN = nrain;
    }
}

// ---------------------------------------------------------------------------
extern "C" void kernel_launch(void* const* d_in, const int* in_sizes, int n_in,
                              void* d_out, int out_size, void* d_ws, size_t ws_size,
                              hipStream_t stream)
{
    const float* hyd  = (const float*)d_in[0];
    const float* W0   = (const float*)d_in[1];
    const float* b0   = (const float*)d_in[2];
    const float* W1   = (const float*)d_in[3];
    const float* b1   = (const float*)d_in[4];
    const float* Win  = (const float*)d_in[5];
    const float* bin  = (const float*)d_in[6];
    const float* Wout = (const float*)d_in[7];
    const float* bout = (const float*)d_in[8];
    float* out = (float*)d_out;
    float* bf  = (float*)d_ws;

    baseflow_kernel<<<BATCH, 256, 0, stream>>>(hyd, bf);
    hyd_step_kernel<<<BATCH / 16, 64, 0, stream>>>(
        hyd, W0, b0, W1, b1, Win, bin, Wout, bout, bf, out);
}

// Round 7
// 4255.882 us; speedup vs baseline: 1.2844x; 1.2844x over previous
//
#include <hip/hip_runtime.h>
#include <hip/hip_bf16.h>
#include <math.h>

#define STEPS 2048
#define BATCH 512

typedef __attribute__((ext_vector_type(8))) short short8;
typedef __attribute__((ext_vector_type(4))) short short4v;
typedef __attribute__((ext_vector_type(2))) short short2v;
typedef __attribute__((ext_vector_type(4))) float f32x4;

__device__ __forceinline__ short f2bf(float f) {
    union { float f; unsigned u; } v; v.f = f;
    unsigned u = v.u;
    return (short)((u + 0x7FFFu + ((u >> 16) & 1u)) >> 16);  // RNE
}
__device__ __forceinline__ short2v pk2(float a, float b) {
    __hip_bfloat162 h = __float22bfloat162_rn(make_float2(a, b));
    union { __hip_bfloat162 h; short2v s; } u; u.h = h; return u.s;
}

// ---------------------------------------------------------------------------
// baseflow[b] = 25th percentile (linear interp) of flow[:, b]
// ---------------------------------------------------------------------------
__global__ __launch_bounds__(256) void baseflow_kernel(
    const float* __restrict__ hyd, float* __restrict__ bf)
{
    __shared__ float arr[STEPS];
    const int b = blockIdx.x;
    const int tid = threadIdx.x;
    for (int t = tid; t < STEPS; t += 256)
        arr[t] = hyd[(size_t)(t * BATCH + b) * 17];
    __syncthreads();
    for (int k = 2; k <= STEPS; k <<= 1) {
        for (int j = k >> 1; j > 0; j >>= 1) {
            for (int i = tid; i < STEPS; i += 256) {
                int ixj = i ^ j;
                if (ixj > i) {
                    float a = arr[i], c = arr[ixj];
                    bool up = ((i & k) == 0);
                    if (up ? (a > c) : (a < c)) { arr[i] = c; arr[ixj] = a; }
                }
            }
            __syncthreads();
        }
    }
    if (tid == 0) bf[b] = arr[511] + 0.75f * (arr[512] - arr[511]);
}

// ---------------------------------------------------------------------------
// 256 blocks x 256 threads (4 waves), 2 batch columns per block, 1 block/CU.
// Critical-path layout (2 barriers/step):
//  - x/rain prefetched global->register one step ahead (no LDS ring)
//  - L0 computed FULLY REDUNDANTLY by each wave (W0aug: 0.01-fold on k16..23,
//    b0 at k=24 via 1.0 B-slot) -> full h1 per wave, in-wave LDS transpose
//    (lgkmcnt ordering only, no barrier)
//  - L1: 2 M-tiles per wave -> shared frag-major h2F -> B1
//  - heads: 6 tiles split 2/2/1/1 -> exp/sigmoid epilogue -> hb -> B2
//  - tail: per-lane redundant (col = lane&1), all registers, no shuffles;
//    lanes 32/33 (cg==2, cn<2) self-produce the stores B-frag for next L0
// ---------------------------------------------------------------------------
__global__ __launch_bounds__(256, 1) void hyd_step_kernel(
    const float* __restrict__ hyd,
    const float* __restrict__ W0,  const float* __restrict__ b0,
    const float* __restrict__ W1,  const float* __restrict__ b1,
    const float* __restrict__ Win, const float* __restrict__ bin,
    const float* __restrict__ Wout,const float* __restrict__ bout,
    const float* __restrict__ baseflow,
    float* __restrict__ out)
{
    __shared__ __align__(16) short h1T[4][256];    // [wv][n*128 + k], bf16
    __shared__ __align__(16) short h2F[256 * 8];   // frag-major shared h2
    __shared__ __align__(16) float hb[2 * 100];    // [col*100 + m], stride-100 pad

    const int tid  = threadIdx.x;
    const int blk  = blockIdx.x;
    const int lane = tid & 63;
    const int wv   = tid >> 6;
    const int cn   = lane & 15;
    const int cg   = lane >> 4;
    const int col  = lane & 1;
    const int nn   = cn & 1;

    // ---- one-time register preload ----
    short8 a0[8];                  // W0aug, all 8 M-tiles (redundant L0)
    short8 a1[2][4]; f32x4 c1[2];  // W1 rows for this wave's 2 M-tiles
    short8 ah[2][4]; f32x4 ch[2];  // head tiles for this wave
    #pragma unroll
    for (int mt = 0; mt < 8; ++mt) {
        const int row = mt * 16 + cn;
        #pragma unroll
        for (int j = 0; j < 8; ++j) {
            const int k = cg * 8 + j;
            float w;
            if (k < 16)       w = W0[row * 24 + k];
            else if (k < 24)  w = 0.01f * W0[row * 24 + k];
            else if (k == 24) w = b0[row];
            else              w = 0.f;
            a0[mt][j] = f2bf(w);
        }
    }
    #pragma unroll
    for (int i = 0; i < 2; ++i) {
        const int row = (2 * wv + i) * 16 + cn;
        #pragma unroll
        for (int kt = 0; kt < 4; ++kt)
            #pragma unroll
            for (int j = 0; j < 8; ++j)
                a1[i][kt][j] = f2bf(W1[row * 128 + kt * 32 + cg * 8 + j]);
        #pragma unroll
        for (int r = 0; r < 4; ++r)
            c1[i][r] = b1[(2 * wv + i) * 16 + cg * 4 + r];
    }
    const int nht = (wv < 2) ? 2 : 1;
    int htile[2];
    htile[0] = (wv < 2) ? 2 * wv : 4 + (wv - 2);
    htile[1] = (wv < 2) ? 2 * wv + 1 : htile[0];
    #pragma unroll
    for (int i = 0; i < 2; ++i) {
        const int ht = htile[i];
        const int row = ht * 16 + cn;
        #pragma unroll
        for (int kt = 0; kt < 4; ++kt)
            #pragma unroll
            for (int j = 0; j < 8; ++j) {
                const int k = kt * 32 + cg * 8 + j;
                float w = 0.f;
                if (row < 9)       w = Win[row * 128 + k];
                else if (row < 89) w = Wout[(row - 9) * 128 + k];
                ah[i][kt][j] = f2bf(w);
            }
        #pragma unroll
        for (int r = 0; r < 4; ++r) {
            const int m = ht * 16 + cg * 4 + r;
            float bb = 0.f;
            if (m < 9)       bb = bin[m];
            else if (m < 89) bb = bout[m - 9];
            ch[i][r] = bb;
        }
    }

    // ---- recurrent state: lane owns column col (redundant across lanes) ----
    float sreg[8];
    #pragma unroll
    for (int j = 0; j < 8; ++j) sreg[j] = (j == 1) ? 1.f : 0.f;
    short8 sp;   // bf16(stores) raw — 0.01 folded into W0aug
    #pragma unroll
    for (int jj = 0; jj < 4; ++jj) {
        short2v p = pk2(sreg[2 * jj], sreg[2 * jj + 1]);
        sp[2 * jj] = p[0]; sp[2 * jj + 1] = p[1];
    }
    short8 onef = (short8)0; onef[0] = (short)0x3F80;   // B[24][n] = 1.0
    const float bfv = baseflow[blk * 2 + col];

    // ---- x/rain prefetch, one step ahead ----
    const bool xact = (cg < 2 && cn < 2);
    const float* xbase = hyd + (size_t)(blk * 2 + cn) * 17 + 1;   // col cn
    const float* rbase = hyd + (size_t)(blk * 2 + col) * 17 + 1;  // col col
    float xf[8];
    #pragma unroll
    for (int j = 0; j < 8; ++j) xf[j] = 0.f;
    if (xact) {
        #pragma unroll
        for (int j = 0; j < 8; ++j) xf[j] = xbase[cg * 8 + j];
    }
    float rainN = rbase[0];

    #pragma unroll 1
    for (int t = 0; t < STEPS; ++t) {
        const float rain = rainN;
        // pack current x into the L0 B-frag (meaningful on cg<2, cn<2)
        short8 xq;
        #pragma unroll
        for (int jj = 0; jj < 4; ++jj) {
            short2v p = pk2(xf[2 * jj], xf[2 * jj + 1]);
            xq[2 * jj] = p[0]; xq[2 * jj + 1] = p[1];
        }
        // issue prefetch for t+1 (consumed next step; latency hidden)
        const size_t off = (size_t)((t + 1 < STEPS) ? (t + 1) : t) * (BATCH * 17);
        float nx[8];
        #pragma unroll
        for (int j = 0; j < 8; ++j) nx[j] = 0.f;
        if (xact) {
            #pragma unroll
            for (int j = 0; j < 8; ++j) nx[j] = xbase[off + cg * 8 + j];
        }
        const float nrain = rbase[off];

        // === L0 (redundant per wave): h1 = relu(W0aug @ [x, stores, 1]) ===
        short8 bf0 = (cg < 2) ? xq : ((cg == 2) ? sp : onef);
        #pragma unroll
        for (int mt = 0; mt < 8; ++mt) {
            f32x4 z = {0.f, 0.f, 0.f, 0.f};
            f32x4 acc = __builtin_amdgcn_mfma_f32_16x16x32_bf16(a0[mt], bf0, z, 0, 0, 0);
            if (cn < 2) {
                short4v p;
                short2v pa = pk2(fmaxf(acc[0], 0.f), fmaxf(acc[1], 0.f));
                short2v pb = pk2(fmaxf(acc[2], 0.f), fmaxf(acc[3], 0.f));
                p[0] = pa[0]; p[1] = pa[1]; p[2] = pb[0]; p[3] = pb[1];
                *(short4v*)&h1T[wv][cn * 128 + mt * 16 + cg * 4] = p;
            }
        }
        // in-wave transpose readback (lgkmcnt ordering only — same wave)
        short8 bh1[4];
        #pragma unroll
        for (int kt = 0; kt < 4; ++kt)
            bh1[kt] = *(const short8*)&h1T[wv][nn * 128 + kt * 32 + cg * 8];

        // === L1: 2 M-tiles per wave ===
        #pragma unroll
        for (int i = 0; i < 2; ++i) {
            f32x4 acc = c1[i];
            #pragma unroll
            for (int kt = 0; kt < 4; ++kt)
                acc = __builtin_amdgcn_mfma_f32_16x16x32_bf16(a1[i][kt], bh1[kt], acc, 0, 0, 0);
            if (cn < 2) {
                const int m0 = (2 * wv + i) * 16 + cg * 4;
                short4v p;
                short2v pa = pk2(fmaxf(acc[0], 0.f), fmaxf(acc[1], 0.f));
                short2v pb = pk2(fmaxf(acc[2], 0.f), fmaxf(acc[3], 0.f));
                p[0] = pa[0]; p[1] = pa[1]; p[2] = pb[0]; p[3] = pb[1];
                *(short4v*)&h2F[((m0 >> 3) * 16 + cn) * 8 + (m0 & 7)] = p;
            }
        }
        __syncthreads();   // B1: h2F published

        // === heads: exp(logits) m<9, sigmoid(gates) 9<=m<89 ===
        short8 bh2[4];
        #pragma unroll
        for (int kt = 0; kt < 4; ++kt)
            bh2[kt] = *(const short8*)&h2F[(kt * 64 + lane) * 8];
        #pragma unroll
        for (int i = 0; i < 2; ++i) {
            if (i < nht) {
                f32x4 acc = ch[i];
                #pragma unroll
                for (int kt = 0; kt < 4; ++kt)
                    acc = __builtin_amdgcn_mfma_f32_16x16x32_bf16(ah[i][kt], bh2[kt], acc, 0, 0, 0);
                if (cn < 2) {
                    const int ht = htile[i];
                    float4 o;
                    #pragma unroll
                    for (int r = 0; r < 4; ++r) {
                        const int m = ht * 16 + cg * 4 + r;
                        const float v = acc[r];
                        const bool isl = (m < 9);
                        const float em = __expf(isl ? v : -v);
                        ((float*)&o)[r] = isl ? em : __builtin_amdgcn_rcpf(1.f + em);
                    }
                    *(float4*)&hb[cn * 100 + ht * 16 + cg * 4] = o;
                }
            }
        }
        __syncthreads();   // B2: hb published

        // === tail: per-lane redundant, column col, all in registers ===
        {
            float gv[92];
            const float4* hp = (const float4*)&hb[col * 100];
            #pragma unroll
            for (int c2 = 0; c2 < 23; ++c2)
                ((float4*)gv)[c2] = hp[c2];

            float den = ((gv[0] + gv[1]) + (gv[2] + gv[3])) +
                        ((gv[4] + gv[5]) + (gv[6] + gv[7])) + gv[8];
            float rr = rain * __builtin_amdgcn_rcpf(den);
            #pragma unroll
            for (int j = 0; j < 8; ++j) sreg[j] += gv[1 + j] * rr;

            #pragma unroll
            for (int d = 0; d < 8; ++d) {
                float fb[8];
                #pragma unroll
                for (int j = 0; j < 8; ++j) fb[j] = gv[9 + d * 8 + j] * sreg[j];
                float fs = ((fb[0] + fb[1]) + (fb[2] + fb[3])) +
                           ((fb[4] + fb[5]) + (fb[6] + fb[7]));
                #pragma unroll
                for (int j = 0; j < 8; ++j) sreg[j] -= fb[j];
                sreg[d] += fs;
            }
            #pragma unroll
            for (int j = 0; j < 8; ++j) sreg[j] -= gv[73 + j] * sreg[j];   // escape
            float fd[8];
            #pragma unroll
            for (int j = 0; j < 8; ++j) fd[j] = gv[81 + j] * sreg[j];      // flow
            float fsum = ((fd[0] + fd[1]) + (fd[2] + fd[3])) +
                         ((fd[4] + fd[5]) + (fd[6] + fd[7]));
            #pragma unroll
            for (int j = 0; j < 8; ++j) sreg[j] -= fd[j];
            if (t == 0) sreg[2] = bfv / fmaxf(gv[83], 1e-5f);   // b_flow[SLOW=2]

            if (tid < 2) out[(size_t)t * BATCH + blk * 2 + tid] = fsum;

            #pragma unroll
            for (int jj = 0; jj < 4; ++jj) {
                short2v p = pk2(sreg[2 * jj], sreg[2 * jj + 1]);
                sp[2 * jj] = p[0]; sp[2 * jj + 1] = p[1];
            }
        }
        // WAR safety: next step's h1T writes are same-wave (lgkmcnt-ordered);
        // h2F(t+1) writes happen after B2(t); hb(t+1) writes after B1(t+1).

        // roll prefetch registers
        #pragma unroll
        for (int j = 0; j < 8; ++j) xf[j] = nx[j];
        rainN = nrain;
    }
}

// ---------------------------------------------------------------------------
extern "C" void kernel_launch(void* const* d_in, const int* in_sizes, int n_in,
                              void* d_out, int out_size, void* d_ws, size_t ws_size,
                              hipStream_t stream)
{
    const float* hyd  = (const float*)d_in[0];
    const float* W0   = (const float*)d_in[1];
    const float* b0   = (const float*)d_in[2];
    const float* W1   = (const float*)d_in[3];
    const float* b1   = (const float*)d_in[4];
    const float* Win  = (const float*)d_in[5];
    const float* bin  = (const float*)d_in[6];
    const float* Wout = (const float*)d_in[7];
    const float* bout = (const float*)d_in[8];
    float* out = (float*)d_out;
    float* bf  = (float*)d_ws;

    baseflow_kernel<<<BATCH, 256, 0, stream>>>(hyd, bf);
    hyd_step_kernel<<<BATCH / 2, 256, 0, stream>>>(
        hyd, W0, b0, W1, b1, Win, bin, Wout, bout, bf, out);
}